// Round 4
// baseline (191.092 us; speedup 1.0000x reference)
//
#include <hip/hip_runtime.h>
#include <stdint.h>
#include <stddef.h>

// b=4, n=1024, dim=512, heads=8, dh=64. qkv ws: [4096][1024] bf16 = Q|K only,
// q pre-scaled by 1/16; V written transposed to vt[b][h][64][1024] bf16.
// fp32->bf16 conversion fused into the GEMMs (no separate convert kernel).

typedef __attribute__((ext_vector_type(4))) float f32x4;
typedef __attribute__((ext_vector_type(8))) short bf16x8;
typedef __attribute__((ext_vector_type(4))) uint32_t u32x4;
typedef __attribute__((ext_vector_type(2))) uint32_t u32x2;

__device__ inline unsigned short f2bf(float f) {
    union { float f; uint32_t u; } cv; cv.f = f;
    uint32_t u = cv.u;
    return (unsigned short)((u + 0x7fffu + ((u >> 16) & 1u)) >> 16);
}
__device__ inline uint32_t packbf2(float lo, float hi) {
    return (uint32_t)f2bf(lo) | ((uint32_t)f2bf(hi) << 16);
}
__device__ inline void gl_lds16(const short* g, short* l) {
    __builtin_amdgcn_global_load_lds(
        (const __attribute__((address_space(1))) void*)g,
        (__attribute__((address_space(3))) void*)l, 16, 0, 0);
}

// ---------------------------------------------------------------------------
// gemm_qkv: qkv = x(fp32) @ w_qkv(fp32, k-major), converted to bf16 on the fly.
// 128m x 128n tile, 256 thr (4 waves of 64x64), BK=32. Grid 32 x 12.
// bn<4: q block (*1/16) -> qkv_b cols 0..511 ; bn 4..7: k -> cols 512..1023;
// bn>=8: v -> vt[b][h][d][j] transposed bf16.
// ---------------------------------------------------------------------------
__global__ __launch_bounds__(256) void gemm_qkv(const float* __restrict__ x,
                                                const float* __restrict__ wqkv,
                                                short* __restrict__ qkv_b,
                                                short* __restrict__ vt) {
    __shared__ __align__(16) short As[128 * 32];
    __shared__ __align__(16) short Bs[128 * 32];
    const int t = threadIdx.x;
    const int lane = t & 63;
    const int wv = t >> 6;
    const int quad = lane >> 4;
    const int l16 = lane & 15;
    const int bm = blockIdx.x / 12;
    const int bn = blockIdx.x % 12;
    const int wm = (wv & 1) * 64, wn = (wv >> 1) * 64;

    f32x4 acc[4][4];
    #pragma unroll
    for (int i = 0; i < 4; i++)
        #pragma unroll
        for (int j = 0; j < 4; j++) acc[i][j] = (f32x4){0.f, 0.f, 0.f, 0.f};

    const int am = t >> 2, ak8 = (t & 3) * 8;   // A-stage: 64 rows per half
    const int kr2 = t & 15, nc = t >> 4;        // B-stage: k-pair x 8-col group

    for (int kt = 0; kt < 16; kt++) {
        // A: x[128m x 32k] fp32 -> As[m][k] bf16
        #pragma unroll
        for (int h = 0; h < 2; h++) {
            int m = h * 64 + am;
            const float* ap = x + (size_t)(bm * 128 + m) * 512 + kt * 32 + ak8;
            f32x4 v0 = *(const f32x4*)ap;
            f32x4 v1 = *(const f32x4*)(ap + 4);
            u32x4 o = {packbf2(v0[0], v0[1]), packbf2(v0[2], v0[3]),
                       packbf2(v1[0], v1[1]), packbf2(v1[2], v1[3])};
            *(u32x4*)(As + m * 32 + ak8) = o;
        }
        // B: wqkv[32k x 128n] fp32 (k-major) -> Bs[n][k] bf16 (transposed), k-pair packed
        {
            const float* bp = wqkv + (size_t)(kt * 32 + kr2 * 2) * 1536 + bn * 128 + nc * 8;
            f32x4 b00 = *(const f32x4*)bp;
            f32x4 b01 = *(const f32x4*)(bp + 4);
            f32x4 b10 = *(const f32x4*)(bp + 1536);
            f32x4 b11 = *(const f32x4*)(bp + 1540);
            #pragma unroll
            for (int i = 0; i < 4; i++) {
                *(uint32_t*)(Bs + (nc * 8 + i) * 32 + kr2 * 2) = packbf2(b00[i], b10[i]);
                *(uint32_t*)(Bs + (nc * 8 + 4 + i) * 32 + kr2 * 2) = packbf2(b01[i], b11[i]);
            }
        }
        __syncthreads();
        bf16x8 af[4], bfr[4];
        #pragma unroll
        for (int mi = 0; mi < 4; mi++)
            af[mi] = *(const bf16x8*)(As + (wm + mi * 16 + l16) * 32 + quad * 8);
        #pragma unroll
        for (int ni = 0; ni < 4; ni++)
            bfr[ni] = *(const bf16x8*)(Bs + (wn + ni * 16 + l16) * 32 + quad * 8);
        #pragma unroll
        for (int mi = 0; mi < 4; mi++)
            #pragma unroll
            for (int ni = 0; ni < 4; ni++)
                acc[mi][ni] = __builtin_amdgcn_mfma_f32_16x16x32_bf16(af[mi], bfr[ni], acc[mi][ni], 0, 0, 0);
        __syncthreads();
    }

    if (bn < 8) {
        const float scq = (bn < 4) ? 0.0625f : 1.0f;
        #pragma unroll
        for (int mi = 0; mi < 4; mi++)
            #pragma unroll
            for (int ni = 0; ni < 4; ni++)
                #pragma unroll
                for (int rg = 0; rg < 4; rg++)
                    qkv_b[(size_t)(bm * 128 + wm + mi * 16 + quad * 4 + rg) * 1024
                          + bn * 128 + wn + ni * 16 + l16] = (short)f2bf(acc[mi][ni][rg] * scq);
    } else {
        #pragma unroll
        for (int mi = 0; mi < 4; mi++) {
            int rowb = bm * 128 + wm + mi * 16 + quad * 4;
            int bbb = rowb >> 10, j = rowb & 1023;
            #pragma unroll
            for (int ni = 0; ni < 4; ni++) {
                int vcol = bn * 128 + wn + ni * 16 + l16 - 1024;   // 0..511
                int hh = vcol >> 6, dd = vcol & 63;
                u32x2 pk = {packbf2(acc[mi][ni][0], acc[mi][ni][1]),
                            packbf2(acc[mi][ni][2], acc[mi][ni][3])};
                *(u32x2*)(vt + ((size_t)((bbb * 8 + hh) * 64 + dd)) * 1024 + j) = pk;
            }
        }
    }
}

// ---------------------------------------------------------------------------
// gemm_out: out(fp32) = ohead(bf16) @ w_out(fp32, k-major -> cvt+transpose).
// 64m x 128n tile, 256 thr (4 waves of 32x64), BK=32. Grid 64 x 4 = 256 blocks.
// ---------------------------------------------------------------------------
__global__ __launch_bounds__(256) void gemm_out(const short* __restrict__ A,
                                                const float* __restrict__ wout,
                                                float* __restrict__ of) {
    __shared__ __align__(16) short As[64 * 32];
    __shared__ __align__(16) short Bs[128 * 32];
    const int t = threadIdx.x;
    const int lane = t & 63;
    const int wv = t >> 6;
    const int quad = lane >> 4;
    const int l16 = lane & 15;
    const int bm = blockIdx.x >> 2;
    const int bn = blockIdx.x & 3;
    const int wm = (wv & 1) * 32, wn = (wv >> 1) * 64;

    f32x4 acc[2][4];
    #pragma unroll
    for (int i = 0; i < 2; i++)
        #pragma unroll
        for (int j = 0; j < 4; j++) acc[i][j] = (f32x4){0.f, 0.f, 0.f, 0.f};

    const int sr = t >> 2, sc = (t & 3) * 8;
    const int kr2 = t & 15, nc = t >> 4;

    for (int kt = 0; kt < 16; kt++) {
        gl_lds16(A + (size_t)(bm * 64 + sr) * 512 + kt * 32 + sc, As + t * 8);
        {
            const float* bp = wout + (size_t)(kt * 32 + kr2 * 2) * 512 + bn * 128 + nc * 8;
            f32x4 b00 = *(const f32x4*)bp;
            f32x4 b01 = *(const f32x4*)(bp + 4);
            f32x4 b10 = *(const f32x4*)(bp + 512);
            f32x4 b11 = *(const f32x4*)(bp + 516);
            #pragma unroll
            for (int i = 0; i < 4; i++) {
                *(uint32_t*)(Bs + (nc * 8 + i) * 32 + kr2 * 2) = packbf2(b00[i], b10[i]);
                *(uint32_t*)(Bs + (nc * 8 + 4 + i) * 32 + kr2 * 2) = packbf2(b01[i], b11[i]);
            }
        }
        __syncthreads();
        bf16x8 af[2], bfr[4];
        #pragma unroll
        for (int mi = 0; mi < 2; mi++)
            af[mi] = *(const bf16x8*)(As + (wm + mi * 16 + l16) * 32 + quad * 8);
        #pragma unroll
        for (int ni = 0; ni < 4; ni++)
            bfr[ni] = *(const bf16x8*)(Bs + (wn + ni * 16 + l16) * 32 + quad * 8);
        #pragma unroll
        for (int mi = 0; mi < 2; mi++)
            #pragma unroll
            for (int ni = 0; ni < 4; ni++)
                acc[mi][ni] = __builtin_amdgcn_mfma_f32_16x16x32_bf16(af[mi], bfr[ni], acc[mi][ni], 0, 0, 0);
        __syncthreads();
    }
    #pragma unroll
    for (int mi = 0; mi < 2; mi++)
        #pragma unroll
        for (int ni = 0; ni < 4; ni++)
            #pragma unroll
            for (int rg = 0; rg < 4; rg++)
                of[(size_t)(bm * 64 + wm + mi * 16 + quad * 4 + rg) * 512
                   + bn * 128 + wn + ni * 16 + l16] = acc[mi][ni][rg];
}

// ---------------------------------------------------------------------------
// Fused entmax-1.5 attention, 16 query rows/block, z in registers.
// K and V^T streamed from global (L2-resident via XCD swizzle). No shift pass:
// Newton runs on raw z from tau0 = rowmax - 1 (root is shift-invariant).
// ---------------------------------------------------------------------------
__global__ __launch_bounds__(256, 4) void attn_entmax(const short* __restrict__ qkv,
                                                      const short* __restrict__ vt,
                                                      short* __restrict__ oheads) {
    __shared__ __align__(16) short P_lds[16 * 1032];     // 33 KB; osum overlays after PV
    __shared__ float redbuf[2][4][16][2];

    float* osum = (float*)P_lds;

    const int t = threadIdx.x;
    const int lane = t & 63;
    const int wv = t >> 6;
    const int quad = lane >> 4;
    const int l16 = lane & 15;

    const int xcd = blockIdx.x & 7;
    const int g = blockIdx.x >> 3;
    const int hb = xcd * 4 + (g >> 6);      // 0..31
    const int rt = g & 63;
    const int bb = hb >> 3, hh = hb & 7;
    const int r0 = rt * 16;

    // Q A-frags (16 real rows); q pre-scaled by 1/16 so z = sim/2 directly
    bf16x8 a0, a1;
    {
        const short* qp = qkv + (size_t)(bb * 1024 + r0 + l16) * 1024 + hh * 64 + quad * 8;
        a0 = *(const bf16x8*)qp;
        a1 = *(const bf16x8*)(qp + 32);
    }

    // ---- scores straight from global K: zf[fi], fi=sup*2+jj,
    //      cols = sup*128 + (wv+4*jj)*16 + l16, rows = quad*4+rg ----
    f32x4 zf[16];
    const short* kb0 = qkv + (size_t)(bb * 1024) * 1024 + 512 + hh * 64 + quad * 8;
    #pragma unroll
    for (int fi = 0; fi < 16; fi++) {
        int sup = fi >> 1, jj = fi & 1;
        int j0 = sup * 128 + (wv + 4 * jj) * 16 + l16;
        const short* kp = kb0 + (size_t)j0 * 1024;
        bf16x8 b0 = *(const bf16x8*)kp;
        bf16x8 b1 = *(const bf16x8*)(kp + 32);
        f32x4 acc = {0.f, 0.f, 0.f, 0.f};
        acc = __builtin_amdgcn_mfma_f32_16x16x32_bf16(a0, b0, acc, 0, 0, 0);
        acc = __builtin_amdgcn_mfma_f32_16x16x32_bf16(a1, b1, acc, 0, 0, 0);
        zf[fi] = acc;
    }

    // ---- row max (for tau0 only — no shift needed, root is shift-invariant) ----
    float mx[4];
    #pragma unroll
    for (int rg = 0; rg < 4; rg++) {
        float m = zf[0][rg];
        #pragma unroll
        for (int fi = 1; fi < 16; fi++) m = fmaxf(m, zf[fi][rg]);
        #pragma unroll
        for (int s = 1; s < 16; s <<= 1) m = fmaxf(m, __shfl_xor(m, s, 64));
        mx[rg] = m;
    }
    if (l16 == 0) {
        #pragma unroll
        for (int rg = 0; rg < 4; rg++) redbuf[0][wv][quad * 4 + rg][0] = mx[rg];
    }
    __syncthreads();
    float tau[4];
    #pragma unroll
    for (int rg = 0; rg < 4; rg++) {
        float m = fmaxf(fmaxf(redbuf[0][0][quad * 4 + rg][0], redbuf[0][1][quad * 4 + rg][0]),
                        fmaxf(redbuf[0][2][quad * 4 + rg][0], redbuf[0][3][quad * 4 + rg][0]));
        tau[rg] = m - 1.0f;                 // f(mx-1) >= 0 -> Newton from below
    }

    // ---- Newton: f(tau)=sum relu(z-tau)^2 - 1, monotone from below ----
    // iter 0 writes redbuf[1] (mx still being read from redbuf[0] is barrier-ordered)
    for (int it = 0; it < 10; it++) {
        const int pp = (~it) & 1;
        float s1[4] = {0.f, 0.f, 0.f, 0.f}, s2[4] = {0.f, 0.f, 0.f, 0.f};
        #pragma unroll
        for (int fi = 0; fi < 16; fi++)
            #pragma unroll
            for (int rg = 0; rg < 4; rg++) {
                float r = fmaxf(zf[fi][rg] - tau[rg], 0.f);
                s1[rg] += r;
                s2[rg] = fmaf(r, r, s2[rg]);
            }
        #pragma unroll
        for (int s = 1; s < 16; s <<= 1)
            #pragma unroll
            for (int rg = 0; rg < 4; rg++) {
                s1[rg] += __shfl_xor(s1[rg], s, 64);
                s2[rg] += __shfl_xor(s2[rg], s, 64);
            }
        if (l16 == 0) {
            #pragma unroll
            for (int rg = 0; rg < 4; rg++) {
                redbuf[pp][wv][quad * 4 + rg][0] = s1[rg];
                redbuf[pp][wv][quad * 4 + rg][1] = s2[rg];
            }
        }
        __syncthreads();
        #pragma unroll
        for (int rg = 0; rg < 4; rg++) {
            int rr = quad * 4 + rg;
            float S1 = redbuf[pp][0][rr][0] + redbuf[pp][1][rr][0]
                     + redbuf[pp][2][rr][0] + redbuf[pp][3][rr][0];
            float S2 = redbuf[pp][0][rr][1] + redbuf[pp][1][rr][1]
                     + redbuf[pp][2][rr][1] + redbuf[pp][3][rr][1];
            tau[rg] += (S2 - 1.f) * 0.5f * __builtin_amdgcn_rcpf(S1);
        }
    }

    // ---- P = relu(z-tau)^2 -> P_lds (bf16, A-operand layout [row][j]) ----
    #pragma unroll
    for (int fi = 0; fi < 16; fi++) {
        int sup = fi >> 1, jj = fi & 1;
        int jbase = sup * 128 + (wv + 4 * jj) * 16;
        #pragma unroll
        for (int rg = 0; rg < 4; rg++) {
            float r = fmaxf(zf[fi][rg] - tau[rg], 0.f);
            P_lds[(quad * 4 + rg) * 1032 + jbase + l16] = (short)f2bf(r * r);
        }
    }
    __syncthreads();

    // ---- PV straight from global V^T: O[r][d] += P[r][j] V[j][d] ----
    f32x4 oacc[4];
    #pragma unroll
    for (int nt = 0; nt < 4; nt++) oacc[nt] = (f32x4){0.f, 0.f, 0.f, 0.f};
    const short* vb0 = vt + (size_t)((bb * 8 + hh) * 64) * 1024;
    #pragma unroll
    for (int sup = 0; sup < 8; sup++) {
        bf16x8 pf = *(const bf16x8*)(P_lds + l16 * 1032 + sup * 128 + wv * 32 + quad * 8);
        #pragma unroll
        for (int nt = 0; nt < 4; nt++) {
            bf16x8 bv = *(const bf16x8*)(vb0 + (size_t)(nt * 16 + l16) * 1024
                                         + sup * 128 + wv * 32 + quad * 8);
            oacc[nt] = __builtin_amdgcn_mfma_f32_16x16x32_bf16(pf, bv, oacc[nt], 0, 0, 0);
        }
    }
    __syncthreads();   // all P reads done; overlay osum on P_lds

    #pragma unroll
    for (int nt = 0; nt < 4; nt++)
        #pragma unroll
        for (int rg = 0; rg < 4; rg++)
            osum[(wv * 16 + quad * 4 + rg) * 68 + nt * 16 + l16] = oacc[nt][rg];
    __syncthreads();
    #pragma unroll
    for (int i = 0; i < 2; i++) {
        int idx = t + 256 * i;              // 512 col-pair tasks
        int r = idx >> 5, dp = idx & 31;
        float e0 = 0.f, e1 = 0.f;
        #pragma unroll
        for (int w = 0; w < 4; w++) {
            e0 += osum[(w * 16 + r) * 68 + dp * 2];
            e1 += osum[(w * 16 + r) * 68 + dp * 2 + 1];
        }
        *(uint32_t*)(oheads + (size_t)(bb * 1024 + r0 + r) * 512 + hh * 64 + dp * 2) = packbf2(e0, e1);
    }
}

// ---------------------------------------------------------------------------
extern "C" void kernel_launch(void* const* d_in, const int* in_sizes, int n_in,
                              void* d_out, int out_size, void* d_ws, size_t ws_size,
                              hipStream_t stream) {
    (void)in_sizes; (void)n_in; (void)out_size; (void)ws_size;
    const float* x     = (const float*)d_in[0];
    const float* w_qkv = (const float*)d_in[1];
    const float* w_out = (const float*)d_in[2];
    float* out = (float*)d_out;

    char* ws = (char*)d_ws;
    short* qkv_b  = (short*)(ws);                        // 8,388,608 B  (Q|K)
    short* vt     = (short*)(ws + 8388608);              // 4,194,304 B  (V^T)
    short* ohead  = (short*)(ws + 12582912);             // 4,194,304 B

    gemm_qkv<<<dim3(32 * 12), dim3(256), 0, stream>>>(x, w_qkv, qkv_b, vt);
    attn_entmax<<<dim3(2048), dim3(256), 0, stream>>>(qkv_b, vt, ohead);
    gemm_out<<<dim3(64 * 4), dim3(256), 0, stream>>>(ohead, w_out, out);
}

// Round 5
// 176.984 us; speedup vs baseline: 1.0797x; 1.0797x over previous
//
#include <hip/hip_runtime.h>
#include <stdint.h>
#include <stddef.h>

// b=4, n=1024, dim=512, heads=8, dh=64. qkv ws: [4096][1024] bf16 = Q|K only,
// q pre-scaled by 1/16; V written transposed to vt[b][h][64][1024] bf16.

typedef __attribute__((ext_vector_type(4))) float f32x4;
typedef __attribute__((ext_vector_type(8))) short bf16x8;
typedef __attribute__((ext_vector_type(4))) uint32_t u32x4;
typedef __attribute__((ext_vector_type(2))) uint32_t u32x2;

__device__ inline unsigned short f2bf(float f) {
    union { float f; uint32_t u; } cv; cv.f = f;
    uint32_t u = cv.u;
    return (unsigned short)((u + 0x7fffu + ((u >> 16) & 1u)) >> 16);
}
__device__ inline uint32_t packbf2(float lo, float hi) {
    return (uint32_t)f2bf(lo) | ((uint32_t)f2bf(hi) << 16);
}
__device__ inline void gl_lds16(const short* g, short* l) {
    __builtin_amdgcn_global_load_lds(
        (const __attribute__((address_space(1))) void*)g,
        (__attribute__((address_space(3))) void*)l, 16, 0, 0);
}

// ---------------------------------------------------------------------------
// convert: x fp32 -> bf16; w_qkv [512][1536] -> wqkvt [1536][512] bf16 (T);
//          w_out [512][512] -> woutt [512][512] bf16 (T)
// ---------------------------------------------------------------------------
__global__ __launch_bounds__(256) void convert_all(const float* __restrict__ x,
                                                   const float* __restrict__ wqkv,
                                                   const float* __restrict__ wout,
                                                   short* __restrict__ xb,
                                                   short* __restrict__ wqkvt,
                                                   short* __restrict__ woutt) {
    __shared__ float tl[32][33];
    const int bid = blockIdx.x;
    const int t = threadIdx.x;
    if (bid < 1024) {                       // x: 2M elems, 2048/block
        int base = bid * 2048 + t * 8;
        f32x4 v0 = *(const f32x4*)(x + base);
        f32x4 v1 = *(const f32x4*)(x + base + 4);
        u32x4 o = {packbf2(v0[0], v0[1]), packbf2(v0[2], v0[3]),
                   packbf2(v1[0], v1[1]), packbf2(v1[2], v1[3])};
        *(u32x4*)(xb + base) = o;
        return;
    }
    const float* src; short* dst; int NC, tn, tk;
    if (bid < 1024 + 768) {                 // w_qkv transpose: 48 x 16 tiles
        int idx = bid - 1024; tn = idx % 48; tk = idx / 48; src = wqkv; dst = wqkvt; NC = 1536;
    } else {                                // w_out transpose: 16 x 16 tiles
        int idx = bid - 1792; tn = idx % 16; tk = idx / 16; src = wout; dst = woutt; NC = 512;
    }
    const int row = t >> 3, c4 = (t & 7) * 4;
    f32x4 v = *(const f32x4*)(src + (size_t)(tk * 32 + row) * NC + tn * 32 + c4);
    tl[row][c4 + 0] = v[0]; tl[row][c4 + 1] = v[1];
    tl[row][c4 + 2] = v[2]; tl[row][c4 + 3] = v[3];
    __syncthreads();
    float a = tl[c4 + 0][row], b = tl[c4 + 1][row];
    float c = tl[c4 + 2][row], d = tl[c4 + 3][row];
    u32x2 o = {packbf2(a, b), packbf2(c, d)};
    *(u32x2*)(dst + (size_t)(tn * 32 + row) * 512 + tk * 32 + c4) = o;
}

// ---------------------------------------------------------------------------
// bf16 MFMA GEMM: 64m x 128n tile, 256 thr (4 waves of 32x64), BK=64 (8 iters).
// MODE 0: out = qkv buffer [M][1024] bf16 (bn<4: *1/16 q; bn 4..7: k) and
//         vt [32][64][1024] transposed (bn>=8 = V cols). MODE 1: fp32 [M][512].
// ---------------------------------------------------------------------------
template<int NB, int MODE>
__global__ __launch_bounds__(256) void gemm_bf16(const short* __restrict__ A,
                                                 const short* __restrict__ Bt,
                                                 void* __restrict__ outp,
                                                 short* __restrict__ vt) {
    __shared__ __align__(16) short As[64 * 64];     // 8 KB
    __shared__ __align__(16) short Bs[128 * 64];    // 16 KB
    const int t = threadIdx.x;
    const int lane = t & 63;
    const int wv = t >> 6;
    const int quad = lane >> 4;
    const int l16 = lane & 15;
    const int bm = blockIdx.x / NB;
    const int bn = blockIdx.x % NB;
    const int wm = (wv & 1) * 32, wn = (wv >> 1) * 64;

    f32x4 acc[2][4];
    #pragma unroll
    for (int i = 0; i < 2; i++)
        #pragma unroll
        for (int j = 0; j < 4; j++) acc[i][j] = (f32x4){0.f, 0.f, 0.f, 0.f};

    const int sr = t >> 3, sc = (t & 7) * 8;        // 32 rows x 64 cols per round

    for (int kt = 0; kt < 8; kt++) {
        #pragma unroll
        for (int h = 0; h < 2; h++)
            gl_lds16(A + (size_t)(bm * 64 + h * 32 + sr) * 512 + kt * 64 + sc,
                     As + (h * 32 + sr) * 64 + sc);
        #pragma unroll
        for (int h = 0; h < 4; h++)
            gl_lds16(Bt + (size_t)(bn * 128 + h * 32 + sr) * 512 + kt * 64 + sc,
                     Bs + (h * 32 + sr) * 64 + sc);
        __syncthreads();
        bf16x8 af[2][2], bfr[4][2];
        #pragma unroll
        for (int mi = 0; mi < 2; mi++)
            #pragma unroll
            for (int kh = 0; kh < 2; kh++)
                af[mi][kh] = *(const bf16x8*)(As + (wm + mi * 16 + l16) * 64 + kh * 32 + quad * 8);
        #pragma unroll
        for (int ni = 0; ni < 4; ni++)
            #pragma unroll
            for (int kh = 0; kh < 2; kh++)
                bfr[ni][kh] = *(const bf16x8*)(Bs + (wn + ni * 16 + l16) * 64 + kh * 32 + quad * 8);
        #pragma unroll
        for (int kh = 0; kh < 2; kh++)
            #pragma unroll
            for (int mi = 0; mi < 2; mi++)
                #pragma unroll
                for (int ni = 0; ni < 4; ni++)
                    acc[mi][ni] = __builtin_amdgcn_mfma_f32_16x16x32_bf16(af[mi][kh], bfr[ni][kh], acc[mi][ni], 0, 0, 0);
        __syncthreads();
    }

    if (MODE == 0) {
        short* ob = (short*)outp;
        if (bn < 8) {
            const float scq = (bn < 4) ? 0.0625f : 1.0f;
            #pragma unroll
            for (int mi = 0; mi < 2; mi++)
                #pragma unroll
                for (int ni = 0; ni < 4; ni++)
                    #pragma unroll
                    for (int rg = 0; rg < 4; rg++)
                        ob[(size_t)(bm * 64 + wm + mi * 16 + quad * 4 + rg) * 1024
                           + bn * 128 + wn + ni * 16 + l16] = (short)f2bf(acc[mi][ni][rg] * scq);
        } else {
            #pragma unroll
            for (int mi = 0; mi < 2; mi++) {
                int rowb = bm * 64 + wm + mi * 16 + quad * 4;
                int bbb = rowb >> 10, j = rowb & 1023;
                #pragma unroll
                for (int ni = 0; ni < 4; ni++) {
                    int vcol = bn * 128 + wn + ni * 16 + l16 - 1024;   // 0..511
                    int hh = vcol >> 6, dd = vcol & 63;
                    u32x2 pk = {packbf2(acc[mi][ni][0], acc[mi][ni][1]),
                                packbf2(acc[mi][ni][2], acc[mi][ni][3])};
                    *(u32x2*)(vt + ((size_t)((bbb * 8 + hh) * 64 + dd)) * 1024 + j) = pk;
                }
            }
        }
    } else {
        float* of = (float*)outp;
        #pragma unroll
        for (int mi = 0; mi < 2; mi++)
            #pragma unroll
            for (int ni = 0; ni < 4; ni++)
                #pragma unroll
                for (int rg = 0; rg < 4; rg++)
                    of[(size_t)(bm * 64 + wm + mi * 16 + quad * 4 + rg) * 512
                       + bn * 128 + wn + ni * 16 + l16] = acc[mi][ni][rg];
    }
}

// ---------------------------------------------------------------------------
// Fused entmax-1.5 attention, 16 query rows/block. Scores in C-layout regs,
// transposed via LDS to row-owner layout: thread (wv,quad,l16) owns all 64
// j-values {i*64 + l16*4 + c} of row quad*4+wv -> Newton is barrier-free with
// 16-lane in-wave reductions. tau0 = full-support closed-form solve clamped
// to the provable bracket [mx-1, mx-1/32].
// ---------------------------------------------------------------------------
__global__ __launch_bounds__(256, 4) void attn_entmax(const short* __restrict__ qkv,
                                                      const short* __restrict__ vt,
                                                      short* __restrict__ oheads) {
    __shared__ __align__(16) short P_lds[16 * 1032];     // 33 KB; zT_buf/osum overlay
    float* zT_buf = (float*)P_lds;                       // [4][1032] fp32 during transpose
    float* osum = (float*)P_lds;

    const int t = threadIdx.x;
    const int lane = t & 63;
    const int wv = t >> 6;
    const int quad = lane >> 4;
    const int l16 = lane & 15;

    const int xcd = blockIdx.x & 7;
    const int g = blockIdx.x >> 3;
    const int hb = xcd * 4 + (g >> 6);      // 0..31
    const int rt = g & 63;
    const int bb = hb >> 3, hh = hb & 7;
    const int r0 = rt * 16;

    // Q A-frags (16 real rows); q pre-scaled by 1/16 so z = sim/2 directly
    bf16x8 a0, a1;
    {
        const short* qp = qkv + (size_t)(bb * 1024 + r0 + l16) * 1024 + hh * 64 + quad * 8;
        a0 = *(const bf16x8*)qp;
        a1 = *(const bf16x8*)(qp + 32);
    }

    // ---- scores from global K: zf[fi], cols = sup*128+(wv+4jj)*16+l16,
    //      rows = quad*4+rg (C-layout) ----
    f32x4 zf[16];
    const short* kb0 = qkv + (size_t)(bb * 1024) * 1024 + 512 + hh * 64 + quad * 8;
    #pragma unroll
    for (int fi = 0; fi < 16; fi++) {
        int sup = fi >> 1, jj = fi & 1;
        int j0 = sup * 128 + (wv + 4 * jj) * 16 + l16;
        const short* kp = kb0 + (size_t)j0 * 1024;
        bf16x8 b0 = *(const bf16x8*)kp;
        bf16x8 b1 = *(const bf16x8*)(kp + 32);
        f32x4 acc = {0.f, 0.f, 0.f, 0.f};
        acc = __builtin_amdgcn_mfma_f32_16x16x32_bf16(a0, b0, acc, 0, 0, 0);
        acc = __builtin_amdgcn_mfma_f32_16x16x32_bf16(a1, b1, acc, 0, 0, 0);
        zf[fi] = acc;
    }

    // ---- transpose to row-owner layout (4 phases, 16.5 KB buffer) ----
    float zT[64];
    for (int q = 0; q < 4; q++) {
        if (quad == q) {
            #pragma unroll
            for (int fi = 0; fi < 16; fi++) {
                int sup = fi >> 1, jj = fi & 1;
                int col = sup * 128 + (wv + 4 * jj) * 16 + l16;
                #pragma unroll
                for (int rg = 0; rg < 4; rg++)
                    zT_buf[rg * 1032 + col] = zf[fi][rg];
            }
        }
        __syncthreads();
        if (quad == q) {
            #pragma unroll
            for (int i = 0; i < 16; i++) {
                f32x4 v = *(const f32x4*)(zT_buf + wv * 1032 + i * 64 + l16 * 4);
                zT[i * 4 + 0] = v[0]; zT[i * 4 + 1] = v[1];
                zT[i * 4 + 2] = v[2]; zT[i * 4 + 3] = v[3];
            }
        }
        __syncthreads();
    }

    // ---- init: mx + full-support closed-form tau, clamped to bracket ----
    float tau;
    {
        float m0 = zT[0], m1 = zT[1], m2 = zT[2], m3 = zT[3];
        float p0 = zT[0], p1 = zT[1], p2 = zT[2], p3 = zT[3];
        float q0 = zT[0] * zT[0], q1 = zT[1] * zT[1], q2 = zT[2] * zT[2], q3 = zT[3] * zT[3];
        #pragma unroll
        for (int i = 1; i < 16; i++) {
            float v0 = zT[i * 4], v1 = zT[i * 4 + 1], v2 = zT[i * 4 + 2], v3 = zT[i * 4 + 3];
            m0 = fmaxf(m0, v0); m1 = fmaxf(m1, v1); m2 = fmaxf(m2, v2); m3 = fmaxf(m3, v3);
            p0 += v0; p1 += v1; p2 += v2; p3 += v3;
            q0 = fmaf(v0, v0, q0); q1 = fmaf(v1, v1, q1);
            q2 = fmaf(v2, v2, q2); q3 = fmaf(v3, v3, q3);
        }
        float mx = fmaxf(fmaxf(m0, m1), fmaxf(m2, m3));
        float s1 = (p0 + p1) + (p2 + p3);
        float s2 = (q0 + q1) + (q2 + q3);
        #pragma unroll
        for (int s = 1; s < 16; s <<= 1) {
            mx = fmaxf(mx, __shfl_xor(mx, s, 64));
            s1 += __shfl_xor(s1, s, 64);
            s2 += __shfl_xor(s2, s, 64);
        }
        float mean = s1 * (1.0f / 1024.0f);
        float disc = fmaxf(mean * mean - (s2 - 1.0f) * (1.0f / 1024.0f), 0.0f);
        tau = mean - __builtin_sqrtf(disc);
        tau = fminf(tau, mx - 0.03125f);    // tau* <= mx - 1/sqrt(n)
        tau = fmaxf(tau, mx - 1.0f);        // tau* >= mx - 1
    }

    // ---- Newton (barrier-free): f(tau)=sum relu(z-tau)^2 - 1, convex ----
    for (int it = 0; it < 8; it++) {
        float a0s = 0.f, a1s = 0.f, a2s = 0.f, a3s = 0.f;
        float b0s = 0.f, b1s = 0.f, b2s = 0.f, b3s = 0.f;
        #pragma unroll
        for (int i = 0; i < 16; i++) {
            float r0 = fmaxf(zT[i * 4] - tau, 0.f);
            float r1 = fmaxf(zT[i * 4 + 1] - tau, 0.f);
            float r2 = fmaxf(zT[i * 4 + 2] - tau, 0.f);
            float r3 = fmaxf(zT[i * 4 + 3] - tau, 0.f);
            a0s += r0; a1s += r1; a2s += r2; a3s += r3;
            b0s = fmaf(r0, r0, b0s); b1s = fmaf(r1, r1, b1s);
            b2s = fmaf(r2, r2, b2s); b3s = fmaf(r3, r3, b3s);
        }
        float s1 = (a0s + a1s) + (a2s + a3s);
        float s2 = (b0s + b1s) + (b2s + b3s);
        #pragma unroll
        for (int s = 1; s < 16; s <<= 1) {
            s1 += __shfl_xor(s1, s, 64);
            s2 += __shfl_xor(s2, s, 64);
        }
        tau += (s2 - 1.0f) * 0.5f * __builtin_amdgcn_rcpf(s1);
    }

    // ---- P = relu(z-tau)^2 -> P_lds[row][j] bf16 (A-operand layout) ----
    {
        const int prow = quad * 4 + wv;
        #pragma unroll
        for (int i = 0; i < 16; i++) {
            float r0 = fmaxf(zT[i * 4] - tau, 0.f);
            float r1 = fmaxf(zT[i * 4 + 1] - tau, 0.f);
            float r2 = fmaxf(zT[i * 4 + 2] - tau, 0.f);
            float r3 = fmaxf(zT[i * 4 + 3] - tau, 0.f);
            u32x2 pk = {packbf2(r0 * r0, r1 * r1), packbf2(r2 * r2, r3 * r3)};
            *(u32x2*)(P_lds + prow * 1032 + i * 64 + l16 * 4) = pk;
        }
    }
    __syncthreads();

    // ---- PV from global V^T: O[r][d] += P[r][j] V[j][d] ----
    f32x4 oacc[4];
    #pragma unroll
    for (int nt = 0; nt < 4; nt++) oacc[nt] = (f32x4){0.f, 0.f, 0.f, 0.f};
    const short* vb0 = vt + (size_t)((bb * 8 + hh) * 64) * 1024;
    #pragma unroll
    for (int sup = 0; sup < 8; sup++) {
        bf16x8 pf = *(const bf16x8*)(P_lds + l16 * 1032 + sup * 128 + wv * 32 + quad * 8);
        #pragma unroll
        for (int nt = 0; nt < 4; nt++) {
            bf16x8 bv = *(const bf16x8*)(vb0 + (size_t)(nt * 16 + l16) * 1024
                                         + sup * 128 + wv * 32 + quad * 8);
            oacc[nt] = __builtin_amdgcn_mfma_f32_16x16x32_bf16(pf, bv, oacc[nt], 0, 0, 0);
        }
    }
    __syncthreads();   // all P reads done; overlay osum on P_lds

    #pragma unroll
    for (int nt = 0; nt < 4; nt++)
        #pragma unroll
        for (int rg = 0; rg < 4; rg++)
            osum[(wv * 16 + quad * 4 + rg) * 68 + nt * 16 + l16] = oacc[nt][rg];
    __syncthreads();
    #pragma unroll
    for (int i = 0; i < 2; i++) {
        int idx = t + 256 * i;              // 512 col-pair tasks
        int r = idx >> 5, dp = idx & 31;
        float e0 = 0.f, e1 = 0.f;
        #pragma unroll
        for (int w = 0; w < 4; w++) {
            e0 += osum[(w * 16 + r) * 68 + dp * 2];
            e1 += osum[(w * 16 + r) * 68 + dp * 2 + 1];
        }
        *(uint32_t*)(oheads + (size_t)(bb * 1024 + r0 + r) * 512 + hh * 64 + dp * 2) = packbf2(e0, e1);
    }
}

// ---------------------------------------------------------------------------
extern "C" void kernel_launch(void* const* d_in, const int* in_sizes, int n_in,
                              void* d_out, int out_size, void* d_ws, size_t ws_size,
                              hipStream_t stream) {
    (void)in_sizes; (void)n_in; (void)out_size; (void)ws_size;
    const float* x     = (const float*)d_in[0];
    const float* w_qkv = (const float*)d_in[1];
    const float* w_out = (const float*)d_in[2];
    float* out = (float*)d_out;

    char* ws = (char*)d_ws;
    short* qkv_b  = (short*)(ws);                        // 8,388,608 B  (Q|K)
    short* vt     = (short*)(ws + 8388608);              // 4,194,304 B  (V^T)
    short* ohead  = (short*)(ws + 12582912);             // 4,194,304 B
    short* xb     = (short*)(ws + 16777216);             // 4,194,304 B
    short* wqkvt  = (short*)(ws + 20971520);             // 1,572,864 B
    short* woutt  = (short*)(ws + 22544384);             //   524,288 B

    convert_all<<<dim3(2048), dim3(256), 0, stream>>>(x, w_qkv, w_out, xb, wqkvt, woutt);
    gemm_bf16<12, 0><<<dim3(64 * 12), dim3(256), 0, stream>>>(xb, wqkvt, (void*)qkv_b, vt);
    attn_entmax<<<dim3(2048), dim3(256), 0, stream>>>(qkv_b, vt, ohead);
    gemm_bf16<4, 1><<<dim3(64 * 4), dim3(256), 0, stream>>>(ohead, woutt, (void*)out, nullptr);
}

// Round 6
// 152.556 us; speedup vs baseline: 1.2526x; 1.1601x over previous
//
#include <hip/hip_runtime.h>
#include <stdint.h>
#include <stddef.h>

// b=4, n=1024, dim=512, heads=8, dh=64. qkv ws: [4096][1024] bf16 = Q|K only,
// q pre-scaled by 1/16; V written transposed to vt[b][h][64][1024] bf16.

typedef __attribute__((ext_vector_type(4))) float f32x4;
typedef __attribute__((ext_vector_type(8))) short bf16x8;
typedef __attribute__((ext_vector_type(4))) uint32_t u32x4;
typedef __attribute__((ext_vector_type(2))) uint32_t u32x2;

__device__ inline unsigned short f2bf(float f) {
    union { float f; uint32_t u; } cv; cv.f = f;
    uint32_t u = cv.u;
    return (unsigned short)((u + 0x7fffu + ((u >> 16) & 1u)) >> 16);
}
__device__ inline uint32_t packbf2(float lo, float hi) {
    return (uint32_t)f2bf(lo) | ((uint32_t)f2bf(hi) << 16);
}
__device__ inline void gl_lds16(const short* g, short* l) {
    __builtin_amdgcn_global_load_lds(
        (const __attribute__((address_space(1))) void*)g,
        (__attribute__((address_space(3))) void*)l, 16, 0, 0);
}

// ---------------------------------------------------------------------------
// convert: x fp32 -> bf16; w_qkv [512][1536] -> wqkvt [1536][512] bf16 (T);
//          w_out [512][512] -> woutt [512][512] bf16 (T)
// ---------------------------------------------------------------------------
__global__ __launch_bounds__(256) void convert_all(const float* __restrict__ x,
                                                   const float* __restrict__ wqkv,
                                                   const float* __restrict__ wout,
                                                   short* __restrict__ xb,
                                                   short* __restrict__ wqkvt,
                                                   short* __restrict__ woutt) {
    __shared__ float tl[32][33];
    const int bid = blockIdx.x;
    const int t = threadIdx.x;
    if (bid < 1024) {                       // x: 2M elems, 2048/block
        int base = bid * 2048 + t * 8;
        f32x4 v0 = *(const f32x4*)(x + base);
        f32x4 v1 = *(const f32x4*)(x + base + 4);
        u32x4 o = {packbf2(v0[0], v0[1]), packbf2(v0[2], v0[3]),
                   packbf2(v1[0], v1[1]), packbf2(v1[2], v1[3])};
        *(u32x4*)(xb + base) = o;
        return;
    }
    const float* src; short* dst; int NC, tn, tk;
    if (bid < 1024 + 768) {                 // w_qkv transpose: 48 x 16 tiles
        int idx = bid - 1024; tn = idx % 48; tk = idx / 48; src = wqkv; dst = wqkvt; NC = 1536;
    } else {                                // w_out transpose: 16 x 16 tiles
        int idx = bid - 1792; tn = idx % 16; tk = idx / 16; src = wout; dst = woutt; NC = 512;
    }
    const int row = t >> 3, c4 = (t & 7) * 4;
    f32x4 v = *(const f32x4*)(src + (size_t)(tk * 32 + row) * NC + tn * 32 + c4);
    tl[row][c4 + 0] = v[0]; tl[row][c4 + 1] = v[1];
    tl[row][c4 + 2] = v[2]; tl[row][c4 + 3] = v[3];
    __syncthreads();
    float a = tl[c4 + 0][row], b = tl[c4 + 1][row];
    float c = tl[c4 + 2][row], d = tl[c4 + 3][row];
    u32x2 o = {packbf2(a, b), packbf2(c, d)};
    *(u32x2*)(dst + (size_t)(tn * 32 + row) * 512 + tk * 32 + c4) = o;
}

// ---------------------------------------------------------------------------
// gemm_qkv: m97-style 128x128 tile, BK=32, 256 thr (4 waves, each 64x64).
// Grid 32 x 12. bn<4: q (*1/16) -> qkv_b cols 0..511; bn 4..7: k -> 512..1023;
// bn>=8: v -> vt[b][h][d][j] transposed bf16.
// ---------------------------------------------------------------------------
__global__ __launch_bounds__(256) void gemm_qkv(const short* __restrict__ A,
                                                const short* __restrict__ Bt,
                                                short* __restrict__ qkv_b,
                                                short* __restrict__ vt) {
    __shared__ __align__(16) short As[128 * 32];
    __shared__ __align__(16) short Bs[128 * 32];
    const int t = threadIdx.x;
    const int lane = t & 63;
    const int wv = t >> 6;
    const int quad = lane >> 4;
    const int l16 = lane & 15;
    const int bm = blockIdx.x / 12;
    const int bn = blockIdx.x % 12;
    const int wm = (wv & 1) * 64, wn = (wv >> 1) * 64;

    f32x4 acc[4][4];
    #pragma unroll
    for (int i = 0; i < 4; i++)
        #pragma unroll
        for (int j = 0; j < 4; j++) acc[i][j] = (f32x4){0.f, 0.f, 0.f, 0.f};

    const int srow = lane >> 2;             // 0..15
    const int scol = (lane & 3) * 8;

    for (int kt = 0; kt < 16; kt++) {
        #pragma unroll
        for (int cc = 0; cc < 2; cc++) {
            int chunk = wv + cc * 4;        // 8 chunks of 16 rows
            gl_lds16(A + (size_t)(bm * 128 + chunk * 16 + srow) * 512 + kt * 32 + scol,
                     As + chunk * 512);
            gl_lds16(Bt + (size_t)(bn * 128 + chunk * 16 + srow) * 512 + kt * 32 + scol,
                     Bs + chunk * 512);
        }
        __syncthreads();
        bf16x8 af[4], bfr[4];
        #pragma unroll
        for (int mi = 0; mi < 4; mi++)
            af[mi] = *(const bf16x8*)(As + (wm + mi * 16 + l16) * 32 + quad * 8);
        #pragma unroll
        for (int ni = 0; ni < 4; ni++)
            bfr[ni] = *(const bf16x8*)(Bs + (wn + ni * 16 + l16) * 32 + quad * 8);
        #pragma unroll
        for (int mi = 0; mi < 4; mi++)
            #pragma unroll
            for (int ni = 0; ni < 4; ni++)
                acc[mi][ni] = __builtin_amdgcn_mfma_f32_16x16x32_bf16(af[mi], bfr[ni], acc[mi][ni], 0, 0, 0);
        __syncthreads();
    }

    if (bn < 8) {
        const float scq = (bn < 4) ? 0.0625f : 1.0f;
        #pragma unroll
        for (int mi = 0; mi < 4; mi++)
            #pragma unroll
            for (int ni = 0; ni < 4; ni++)
                #pragma unroll
                for (int rg = 0; rg < 4; rg++)
                    qkv_b[(size_t)(bm * 128 + wm + mi * 16 + quad * 4 + rg) * 1024
                          + bn * 128 + wn + ni * 16 + l16] = (short)f2bf(acc[mi][ni][rg] * scq);
    } else {
        #pragma unroll
        for (int mi = 0; mi < 4; mi++) {
            int rowb = bm * 128 + wm + mi * 16 + quad * 4;
            int bbb = rowb >> 10, j = rowb & 1023;
            #pragma unroll
            for (int ni = 0; ni < 4; ni++) {
                int vcol = bn * 128 + wn + ni * 16 + l16 - 1024;   // 0..511
                int hh = vcol >> 6, dd = vcol & 63;
                u32x2 pk = {packbf2(acc[mi][ni][0], acc[mi][ni][1]),
                            packbf2(acc[mi][ni][2], acc[mi][ni][3])};
                *(u32x2*)(vt + ((size_t)((bbb * 8 + hh) * 64 + dd)) * 1024 + j) = pk;
            }
        }
    }
}

// ---------------------------------------------------------------------------
// gemm_out: 64m x 128n tile, BK=64, grid 64 x 4 = 256 blocks (1 CU round).
// ---------------------------------------------------------------------------
__global__ __launch_bounds__(256) void gemm_out(const short* __restrict__ A,
                                                const short* __restrict__ Bt,
                                                float* __restrict__ of) {
    __shared__ __align__(16) short As[64 * 64];
    __shared__ __align__(16) short Bs[128 * 64];
    const int t = threadIdx.x;
    const int lane = t & 63;
    const int wv = t >> 6;
    const int quad = lane >> 4;
    const int l16 = lane & 15;
    const int bm = blockIdx.x >> 2;
    const int bn = blockIdx.x & 3;
    const int wm = (wv & 1) * 32, wn = (wv >> 1) * 64;

    f32x4 acc[2][4];
    #pragma unroll
    for (int i = 0; i < 2; i++)
        #pragma unroll
        for (int j = 0; j < 4; j++) acc[i][j] = (f32x4){0.f, 0.f, 0.f, 0.f};

    const int sr = t >> 3, sc = (t & 7) * 8;

    for (int kt = 0; kt < 8; kt++) {
        #pragma unroll
        for (int h = 0; h < 2; h++)
            gl_lds16(A + (size_t)(bm * 64 + h * 32 + sr) * 512 + kt * 64 + sc,
                     As + (h * 32 + sr) * 64 + sc);
        #pragma unroll
        for (int h = 0; h < 4; h++)
            gl_lds16(Bt + (size_t)(bn * 128 + h * 32 + sr) * 512 + kt * 64 + sc,
                     Bs + (h * 32 + sr) * 64 + sc);
        __syncthreads();
        bf16x8 af[2][2], bfr[4][2];
        #pragma unroll
        for (int mi = 0; mi < 2; mi++)
            #pragma unroll
            for (int kh = 0; kh < 2; kh++)
                af[mi][kh] = *(const bf16x8*)(As + (wm + mi * 16 + l16) * 64 + kh * 32 + quad * 8);
        #pragma unroll
        for (int ni = 0; ni < 4; ni++)
            #pragma unroll
            for (int kh = 0; kh < 2; kh++)
                bfr[ni][kh] = *(const bf16x8*)(Bs + (wn + ni * 16 + l16) * 64 + kh * 32 + quad * 8);
        #pragma unroll
        for (int kh = 0; kh < 2; kh++)
            #pragma unroll
            for (int mi = 0; mi < 2; mi++)
                #pragma unroll
                for (int ni = 0; ni < 4; ni++)
                    acc[mi][ni] = __builtin_amdgcn_mfma_f32_16x16x32_bf16(af[mi][kh], bfr[ni][kh], acc[mi][ni], 0, 0, 0);
        __syncthreads();
    }
    #pragma unroll
    for (int mi = 0; mi < 2; mi++)
        #pragma unroll
        for (int ni = 0; ni < 4; ni++)
            #pragma unroll
            for (int rg = 0; rg < 4; rg++)
                of[(size_t)(bm * 64 + wm + mi * 16 + quad * 4 + rg) * 512
                   + bn * 128 + wn + ni * 16 + l16] = acc[mi][ni][rg];
}

// ---------------------------------------------------------------------------
// Fused entmax-1.5 attention, 16 query rows/block. Scores computed in 4
// column-chunks of 256; each chunk is transposed through LDS immediately so
// peak live regs ~= zT(64) + chunk(16) + Q(16) < 128 (no scratch spill).
// Thread (wv,quad,l16) ends owning all 64 j of row quad*4+wv -> barrier-free
// Newton with 16-lane in-wave reductions.
// ---------------------------------------------------------------------------
__global__ __launch_bounds__(256, 4) void attn_entmax(const short* __restrict__ qkv,
                                                      const short* __restrict__ vt,
                                                      short* __restrict__ oheads) {
    __shared__ __align__(16) short P_lds[16 * 1032];     // 33 KB; tbuf/osum overlay
    float* tbuf = (float*)P_lds;                         // [16][268] fp32 transpose buf
    float* osum = (float*)P_lds;

    const int t = threadIdx.x;
    const int lane = t & 63;
    const int wv = t >> 6;
    const int quad = lane >> 4;
    const int l16 = lane & 15;

    const int xcd = blockIdx.x & 7;
    const int g = blockIdx.x >> 3;
    const int hb = xcd * 4 + (g >> 6);      // 0..31
    const int rt = g & 63;
    const int bb = hb >> 3, hh = hb & 7;
    const int r0 = rt * 16;

    // Q A-frags (16 real rows); q pre-scaled by 1/16 so z = sim/2 directly
    bf16x8 a0, a1;
    {
        const short* qp = qkv + (size_t)(bb * 1024 + r0 + l16) * 1024 + hh * 64 + quad * 8;
        a0 = *(const bf16x8*)qp;
        a1 = *(const bf16x8*)(qp + 32);
    }

    // ---- scores in 4 column-chunks of 256, transposed to row-owner layout ----
    // zT[ci*16 + i*4 + c] = z[row quad*4+wv][col ci*256 + i*64 + l16*4 + c]
    float zT[64];
    const short* kb0 = qkv + (size_t)(bb * 1024) * 1024 + 512 + hh * 64 + quad * 8;
    const int rown = quad * 4 + wv;         // owned row
    for (int ci = 0; ci < 4; ci++) {
        f32x4 zc[4];
        #pragma unroll
        for (int f = 0; f < 4; f++) {
            int supl = f >> 1, jj = f & 1;
            int j0 = (ci * 2 + supl) * 128 + (wv + 4 * jj) * 16 + l16;
            const short* kp = kb0 + (size_t)j0 * 1024;
            bf16x8 b0 = *(const bf16x8*)kp;
            bf16x8 b1 = *(const bf16x8*)(kp + 32);
            f32x4 acc = {0.f, 0.f, 0.f, 0.f};
            acc = __builtin_amdgcn_mfma_f32_16x16x32_bf16(a0, b0, acc, 0, 0, 0);
            acc = __builtin_amdgcn_mfma_f32_16x16x32_bf16(a1, b1, acc, 0, 0, 0);
            zc[f] = acc;
        }
        __syncthreads();                    // previous chunk's readback complete
        #pragma unroll
        for (int f = 0; f < 4; f++) {
            int supl = f >> 1, jj = f & 1;
            int colc = supl * 128 + (wv + 4 * jj) * 16 + l16;
            #pragma unroll
            for (int rg = 0; rg < 4; rg++)
                tbuf[(quad * 4 + rg) * 268 + colc] = zc[f][rg];
        }
        __syncthreads();
        #pragma unroll
        for (int i = 0; i < 4; i++) {
            f32x4 v = *(const f32x4*)(tbuf + rown * 268 + i * 64 + l16 * 4);
            zT[ci * 16 + i * 4 + 0] = v[0]; zT[ci * 16 + i * 4 + 1] = v[1];
            zT[ci * 16 + i * 4 + 2] = v[2]; zT[ci * 16 + i * 4 + 3] = v[3];
        }
    }
    __syncthreads();                        // last readback done; P_lds reusable

    // ---- init: mx + full-support closed-form tau, clamped to bracket ----
    float tau;
    {
        float m0 = zT[0], m1 = zT[1], m2 = zT[2], m3 = zT[3];
        float p0 = zT[0], p1 = zT[1], p2 = zT[2], p3 = zT[3];
        float q0 = zT[0] * zT[0], q1 = zT[1] * zT[1], q2 = zT[2] * zT[2], q3 = zT[3] * zT[3];
        #pragma unroll
        for (int i = 1; i < 16; i++) {
            float v0 = zT[i * 4], v1 = zT[i * 4 + 1], v2 = zT[i * 4 + 2], v3 = zT[i * 4 + 3];
            m0 = fmaxf(m0, v0); m1 = fmaxf(m1, v1); m2 = fmaxf(m2, v2); m3 = fmaxf(m3, v3);
            p0 += v0; p1 += v1; p2 += v2; p3 += v3;
            q0 = fmaf(v0, v0, q0); q1 = fmaf(v1, v1, q1);
            q2 = fmaf(v2, v2, q2); q3 = fmaf(v3, v3, q3);
        }
        float mx = fmaxf(fmaxf(m0, m1), fmaxf(m2, m3));
        float s1 = (p0 + p1) + (p2 + p3);
        float s2 = (q0 + q1) + (q2 + q3);
        #pragma unroll
        for (int s = 1; s < 16; s <<= 1) {
            mx = fmaxf(mx, __shfl_xor(mx, s, 64));
            s1 += __shfl_xor(s1, s, 64);
            s2 += __shfl_xor(s2, s, 64);
        }
        float mean = s1 * (1.0f / 1024.0f);
        float disc = fmaxf(mean * mean - (s2 - 1.0f) * (1.0f / 1024.0f), 0.0f);
        tau = mean - __builtin_sqrtf(disc);
        tau = fminf(tau, mx - 0.03125f);    // tau* <= mx - 1/sqrt(n)
        tau = fmaxf(tau, mx - 1.0f);        // tau* >= mx - 1
    }

    // ---- Newton (barrier-free): f(tau)=sum relu(z-tau)^2 - 1, convex ----
    for (int it = 0; it < 8; it++) {
        float a0s = 0.f, a1s = 0.f, a2s = 0.f, a3s = 0.f;
        float b0s = 0.f, b1s = 0.f, b2s = 0.f, b3s = 0.f;
        #pragma unroll
        for (int i = 0; i < 16; i++) {
            float r0 = fmaxf(zT[i * 4] - tau, 0.f);
            float r1 = fmaxf(zT[i * 4 + 1] - tau, 0.f);
            float r2 = fmaxf(zT[i * 4 + 2] - tau, 0.f);
            float r3 = fmaxf(zT[i * 4 + 3] - tau, 0.f);
            a0s += r0; a1s += r1; a2s += r2; a3s += r3;
            b0s = fmaf(r0, r0, b0s); b1s = fmaf(r1, r1, b1s);
            b2s = fmaf(r2, r2, b2s); b3s = fmaf(r3, r3, b3s);
        }
        float s1 = (a0s + a1s) + (a2s + a3s);
        float s2 = (b0s + b1s) + (b2s + b3s);
        #pragma unroll
        for (int s = 1; s < 16; s <<= 1) {
            s1 += __shfl_xor(s1, s, 64);
            s2 += __shfl_xor(s2, s, 64);
        }
        tau += (s2 - 1.0f) * 0.5f * __builtin_amdgcn_rcpf(s1);
    }

    // ---- P = relu(z-tau)^2 -> P_lds[row][j] bf16 (A-operand layout) ----
    #pragma unroll
    for (int ci = 0; ci < 4; ci++)
        #pragma unroll
        for (int i = 0; i < 4; i++) {
            float r0 = fmaxf(zT[ci * 16 + i * 4 + 0] - tau, 0.f);
            float r1 = fmaxf(zT[ci * 16 + i * 4 + 1] - tau, 0.f);
            float r2 = fmaxf(zT[ci * 16 + i * 4 + 2] - tau, 0.f);
            float r3 = fmaxf(zT[ci * 16 + i * 4 + 3] - tau, 0.f);
            u32x2 pk = {packbf2(r0 * r0, r1 * r1), packbf2(r2 * r2, r3 * r3)};
            *(u32x2*)(P_lds + rown * 1032 + ci * 256 + i * 64 + l16 * 4) = pk;
        }
    __syncthreads();

    // ---- PV from global V^T: O[r][d] += P[r][j] V[j][d] ----
    f32x4 oacc[4];
    #pragma unroll
    for (int nt = 0; nt < 4; nt++) oacc[nt] = (f32x4){0.f, 0.f, 0.f, 0.f};
    const short* vb0 = vt + (size_t)((bb * 8 + hh) * 64) * 1024;
    #pragma unroll
    for (int sup = 0; sup < 8; sup++) {
        bf16x8 pf = *(const bf16x8*)(P_lds + l16 * 1032 + sup * 128 + wv * 32 + quad * 8);
        #pragma unroll
        for (int nt = 0; nt < 4; nt++) {
            bf16x8 bv = *(const bf16x8*)(vb0 + (size_t)(nt * 16 + l16) * 1024
                                         + sup * 128 + wv * 32 + quad * 8);
            oacc[nt] = __builtin_amdgcn_mfma_f32_16x16x32_bf16(pf, bv, oacc[nt], 0, 0, 0);
        }
    }
    __syncthreads();   // all P reads done; overlay osum on P_lds

    #pragma unroll
    for (int nt = 0; nt < 4; nt++)
        #pragma unroll
        for (int rg = 0; rg < 4; rg++)
            osum[(wv * 16 + quad * 4 + rg) * 68 + nt * 16 + l16] = oacc[nt][rg];
    __syncthreads();
    #pragma unroll
    for (int i = 0; i < 2; i++) {
        int idx = t + 256 * i;              // 512 col-pair tasks
        int r = idx >> 5, dp = idx & 31;
        float e0 = 0.f, e1 = 0.f;
        #pragma unroll
        for (int w = 0; w < 4; w++) {
            e0 += osum[(w * 16 + r) * 68 + dp * 2];
            e1 += osum[(w * 16 + r) * 68 + dp * 2 + 1];
        }
        *(uint32_t*)(oheads + (size_t)(bb * 1024 + r0 + r) * 512 + hh * 64 + dp * 2) = packbf2(e0, e1);
    }
}

// ---------------------------------------------------------------------------
extern "C" void kernel_launch(void* const* d_in, const int* in_sizes, int n_in,
                              void* d_out, int out_size, void* d_ws, size_t ws_size,
                              hipStream_t stream) {
    (void)in_sizes; (void)n_in; (void)out_size; (void)ws_size;
    const float* x     = (const float*)d_in[0];
    const float* w_qkv = (const float*)d_in[1];
    const float* w_out = (const float*)d_in[2];
    float* out = (float*)d_out;

    char* ws = (char*)d_ws;
    short* qkv_b  = (short*)(ws);                        // 8,388,608 B  (Q|K)
    short* vt     = (short*)(ws + 8388608);              // 4,194,304 B  (V^T)
    short* ohead  = (short*)(ws + 12582912);             // 4,194,304 B
    short* xb     = (short*)(ws + 16777216);             // 4,194,304 B
    short* wqkvt  = (short*)(ws + 20971520);             // 1,572,864 B
    short* woutt  = (short*)(ws + 22544384);             //   524,288 B

    convert_all<<<dim3(2048), dim3(256), 0, stream>>>(x, w_qkv, w_out, xb, wqkvt, woutt);
    gemm_qkv<<<dim3(32 * 12), dim3(256), 0, stream>>>(xb, wqkvt, qkv_b, vt);
    attn_entmax<<<dim3(2048), dim3(256), 0, stream>>>(qkv_b, vt, ohead);
    gemm_out<<<dim3(64 * 4), dim3(256), 0, stream>>>(ohead, woutt, out);
}